// Round 16
// baseline (627.414 us; speedup 1.0000x reference)
//
#include <hip/hip_runtime.h>

typedef unsigned long long u64;
typedef unsigned int u32;

// Problem constants (from reference setup_inputs / NUM_GROUP / GROUP_SIZE)
#define BATCH 32
#define NPTS  8192
#define NGRP  512
#define KNN_K 32

#define FPS_T 256                  // fps block (4 waves) -- champion config
#define FPS_W (FPS_T / 64)         // 4 waves
#define PPT   (NPTS / FPS_T)       // 32 points per thread (scalar regs)
#define KNN_WPB 4                  // knn waves per block
#define QCAP 128                   // per-wave LDS candidate buffer depth

// Exact IEEE (no FMA contraction) squared distance: ((dx*dx + dy*dy) + dz*dz)
__device__ __forceinline__ float sq3(float dx, float dy, float dz) {
    return __fadd_rn(__fadd_rn(__fmul_rn(dx, dx), __fmul_rn(dy, dy)), __fmul_rn(dz, dz));
}

// d >= 0 always -> IEEE bits order-monotonic; u64 ascending == (d, idx) lex.
__device__ __forceinline__ u64 packdi(float d, int n) {
    return ((u64)__float_as_uint(d) << 32) | (u32)n;
}

__device__ __forceinline__ u64 umin64(u64 a, u64 b) { return a < b ? a : b; }
__device__ __forceinline__ u64 umax64(u64 a, u64 b) { return a > b ? a : b; }

__device__ __forceinline__ u64 shfl_xor_u64(u64 v, int m) {
    int lo = __shfl_xor((int)(u32)v, m, 64);
    int hi = __shfl_xor((int)(u32)(v >> 32), m, 64);
    return ((u64)(u32)hi << 32) | (u32)lo;
}

__device__ __forceinline__ u64 shfl_u64(u64 v, int src) {
    int lo = __shfl((int)(u32)v, src, 64);
    int hi = __shfl((int)(u32)(v >> 32), src, 64);
    return ((u64)(u32)hi << 32) | (u32)lo;
}

// ---- DPP wave-64 u64-max reduction (result valid in lane 63) --------------
// update_dpp(old=0, bound_ctrl=1): invalid-source lanes read 0; 0 is a safe
// identity (real keys have low32 = ~n >= 0xFFFFE000 > 0).
template <int CTRL>
__device__ __forceinline__ u64 dpp_max_step(u64 k) {
    u32 plo = (u32)__builtin_amdgcn_update_dpp(0, (int)(u32)k, CTRL, 0xF, 0xF, true);
    u32 phi = (u32)__builtin_amdgcn_update_dpp(0, (int)(u32)(k >> 32), CTRL, 0xF, 0xF, true);
    u64 p = ((u64)phi << 32) | plo;
    return k > p ? k : p;
}
__device__ __forceinline__ u64 dpp_wave_max(u64 k) {
    k = dpp_max_step<0x111>(k);  // row_shr:1
    k = dpp_max_step<0x112>(k);  // row_shr:2
    k = dpp_max_step<0x114>(k);  // row_shr:4
    k = dpp_max_step<0x118>(k);  // row_shr:8
    k = dpp_max_step<0x142>(k);  // row_bcast15
    k = dpp_max_step<0x143>(k);  // row_bcast31 -> lane63 = full wave
    return k;
}

// Cross-lane bitonic sort: one u64 per lane -> ascending by lane index.
__device__ __forceinline__ u64 lane_sort64(u64 v, int lane) {
#pragma unroll
    for (int k = 2; k <= 64; k <<= 1) {
#pragma unroll
        for (int j = k >> 1; j > 0; j >>= 1) {
            u64 p = shfl_xor_u64(v, j);
            bool keepmin = (((lane & k) == 0) == ((lane & j) == 0));
            u64 mn = umin64(v, p), mx = umax64(v, p);
            v = keepmin ? mn : mx;
        }
    }
    return v;
}

// m, c ascending-sorted across lanes -> lowest 64 of the 128, sorted.
__device__ __forceinline__ u64 lane_merge64(u64 m, u64 c, int lane) {
    u64 cr = shfl_xor_u64(c, 63);
    u64 z = umin64(m, cr);
#pragma unroll
    for (int dd = 32; dd > 0; dd >>= 1) {
        u64 p = shfl_xor_u64(z, dd);
        u64 mn = umin64(z, p), mx = umax64(z, p);
        z = (lane & dd) ? mx : mn;
    }
    return z;
}

// One knn scan step: tau-filter + ballot-compacted LDS append + batched flush
__device__ __forceinline__ void knn_step(u64& m, u64& tau, int& cnt, u64* sbuf,
                                         float x, float y, float z,
                                         float cx, float cy, float cz,
                                         int n, int lane) {
    float d = sq3(__fsub_rn(x, cx), __fsub_rn(y, cy), __fsub_rn(z, cz));
    u64 kk = packdi(d, n);
    bool cand = kk < tau;  // strict: excluded keys provably > global 32nd
    u64 mask = __ballot(cand);
    if (mask) {
        u32 below = __builtin_amdgcn_mbcnt_hi(
            (u32)(mask >> 32), __builtin_amdgcn_mbcnt_lo((u32)mask, 0));
        if (cand) sbuf[cnt + below] = kk;
        cnt += (int)__popcll(mask);
        if (cnt >= 64) {
            u64 c = sbuf[lane];
            c = lane_sort64(c, lane);
            m = lane_merge64(m, c, lane);
            tau = shfl_u64(m, 31);
            int rem = cnt - 64;
            if (lane < rem) sbuf[lane] = sbuf[64 + lane];
            cnt = rem;
        }
    }
}

// ---------------------------------------------------------------------------
// FPS (champion structure + R16 tail cut): one block per batch, 256 threads,
// 32 points/thread in scalar register arrays. Round loop: per-point distance
// (per-op IEEE == numpy) + fmin + slot tracking (strict >, inline-const
// cndmask; lowest slot == lowest n). u64 (d_bits,~bi) DPP wave argmax; lane
// 63 PREFETCHES its wave winner's coords from the LDS mirror before the
// barrier and publishes (key, x, y, z). Post-barrier: ONE LDS trip reads
// 4 keys + 12 coord-b32s (same-address broadcasts, conflict-free -- NOT
// b128, which serializes on broadcast per R6) + 3-level cndmask tournament.
// No second dependent LDS trip, no 'cur' index. Centers buffered in LDS,
// written coalesced once at the end.
// ---------------------------------------------------------------------------
__global__ __launch_bounds__(FPS_T) void fps_kernel(const float* __restrict__ in,
                                                    float* __restrict__ centers) {
    __shared__ float sx[NPTS];           // 32 KB
    __shared__ float sy[NPTS];           // 32 KB
    __shared__ float sz[NPTS];           // 32 KB
    __shared__ u64   s_key[2][FPS_W];    // double-buffered wave keys
    __shared__ float s_wc[2][3][FPS_W];  // double-buffered wave-winner coords
    __shared__ float s_out[NGRP * 3];    // 6 KB center-coord buffer

    const int b = blockIdx.x;
    const int t = threadIdx.x;
    const int w = t >> 6;
    const int lane = t & 63;
    const float* xp = in + (size_t)b * 3 * NPTS;
    const float* yp = xp + NPTS;
    const float* zp = xp + 2 * NPTS;

    float xr[PPT], yr[PPT], zr[PPT], md[PPT];
#pragma unroll
    for (int i = 0; i < PPT; ++i) {
        int n = i * FPS_T + t;
        float x = xp[n], y = yp[n], z = zp[n];
        xr[i] = x; yr[i] = y; zr[i] = z;
        sx[n] = x; sy[n] = y; sz[n] = z;
        md[i] = 1e10f;
    }
    __syncthreads();

    // round-0 centroid = point 0 (broadcast reads)
    float cx = sx[0], cy = sy[0], cz = sz[0];

    for (int r = 0; r < NGRP; ++r) {
        if (t == 0) {  // idxs[r] is the PRE-update farthest -> buffer coords
            s_out[r * 3 + 0] = cx;
            s_out[r * 3 + 1] = cy;
            s_out[r * 3 + 2] = cz;
        }

        float bd = -1.0f;
        int   s  = 0;
#pragma unroll
        for (int i = 0; i < PPT; ++i) {
            float d = sq3(__fsub_rn(xr[i], cx), __fsub_rn(yr[i], cy),
                          __fsub_rn(zr[i], cz));
            md[i] = fminf(md[i], d);
            if (md[i] > bd) { bd = md[i]; s = i; }  // strict >: first (lowest) slot
        }
        const int bi = (s << 8) + t;  // lowest slot == lowest n for fixed t
        // max (d, tie -> lowest n) == u64 max of (d_bits, ~n)
        u64 k = ((u64)__float_as_uint(bd) << 32) | (u32)(~(u32)bi);
        k = dpp_wave_max(k);
        if (lane == 63) {  // publish key + prefetched winner coords
            const int nw = (int)(~(u32)k) & (NPTS - 1);
            const float wx = sx[nw], wy = sy[nw], wz = sz[nw];
            s_key[r & 1][w] = k;
            s_wc[r & 1][0][w] = wx;
            s_wc[r & 1][1][w] = wy;
            s_wc[r & 1][2][w] = wz;
        }
        __syncthreads();
        // ONE LDS trip: 4 keys + 12 coords, all same-address b32/b64 broadcasts
        const u64 k0 = s_key[r & 1][0], k1 = s_key[r & 1][1];
        const u64 k2 = s_key[r & 1][2], k3 = s_key[r & 1][3];
        const float x0 = s_wc[r & 1][0][0], y0 = s_wc[r & 1][1][0], z0 = s_wc[r & 1][2][0];
        const float x1 = s_wc[r & 1][0][1], y1 = s_wc[r & 1][1][1], z1 = s_wc[r & 1][2][1];
        const float x2 = s_wc[r & 1][0][2], y2 = s_wc[r & 1][1][2], z2 = s_wc[r & 1][2][2];
        const float x3 = s_wc[r & 1][0][3], y3 = s_wc[r & 1][1][3], z3 = s_wc[r & 1][2][3];
        // 3-level tournament (ties impossible: ~n unique across waves)
        const bool a01 = (k0 >= k1);
        const u64  m01 = a01 ? k0 : k1;
        const float xa = a01 ? x0 : x1, ya = a01 ? y0 : y1, za = a01 ? z0 : z1;
        const bool a23 = (k2 >= k3);
        const u64  m23 = a23 ? k2 : k3;
        const float xb = a23 ? x2 : x3, yb = a23 ? y2 : y3, zb = a23 ? z2 : z3;
        const bool af = (m01 >= m23);
        cx = af ? xa : xb;
        cy = af ? ya : yb;
        cz = af ? za : zb;
    }

    __syncthreads();  // t0's last s_out writes
    float* cdst = centers + (size_t)b * NGRP * 3;
    for (int i = t; i < NGRP * 3; i += FPS_T) cdst[i] = s_out[i];
}

// ---------------------------------------------------------------------------
// kNN + gather: R8/R11 wave-cooperative exact top-32 core with 8-column
// hoisted loads (24 independent loads in flight; R15's 4-col gained ~20 us).
// Flush/merge identical -- same keys, same order, bit-exact.
// ---------------------------------------------------------------------------
__global__ __launch_bounds__(KNN_WPB * 64) void knn_kernel(const float* __restrict__ in,
                                                           const float* __restrict__ centers,
                                                           float* __restrict__ out) {
    __shared__ u64 sbuf[KNN_WPB][QCAP];  // 4 KB candidate buffers

    const int wave = threadIdx.x >> 6;
    const int lane = threadIdx.x & 63;
    const int cid  = blockIdx.x * KNN_WPB + wave;   // [0, B*G)
    const int b    = cid >> 9;                      // /NGRP

    const float* xp = in + (size_t)b * 3 * NPTS;
    const float* yp = xp + NPTS;
    const float* zp = xp + 2 * NPTS;

    const float cx = centers[cid * 3 + 0];
    const float cy = centers[cid * 3 + 1];
    const float cz = centers[cid * 3 + 2];

    // seed: column 0 (points 0..63), exact sorted top-64
    float x = xp[lane], y = yp[lane], z = zp[lane];
    u64 m = packdi(sq3(__fsub_rn(x, cx), __fsub_rn(y, cy), __fsub_rn(z, cz)), lane);
    m = lane_sort64(m, lane);
    u64 tau = shfl_u64(m, 31);
    int cnt = 0;  // wave-uniform buffered-candidate count

    // 8-column unrolled scan: 24 hoisted independent loads per iteration
    int j = 1;
#pragma unroll 1
    for (; j + 7 < NPTS / 64; j += 8) {
        int n0 = j * 64 + lane;
        float xv[8], yv[8], zv[8];
#pragma unroll
        for (int q = 0; q < 8; ++q) {
            xv[q] = xp[n0 + q * 64];
            yv[q] = yp[n0 + q * 64];
            zv[q] = zp[n0 + q * 64];
        }
#pragma unroll
        for (int q = 0; q < 8; ++q)
            knn_step(m, tau, cnt, sbuf[wave], xv[q], yv[q], zv[q],
                     cx, cy, cz, n0 + q * 64, lane);
    }
    for (; j < NPTS / 64; ++j) {
        int n = j * 64 + lane;
        knn_step(m, tau, cnt, sbuf[wave], xp[n], yp[n], zp[n], cx, cy, cz, n, lane);
    }
    // drain leftovers (<= 127 keys -> at most 2 batches)
    while (cnt > 0) {
        int take = cnt < 64 ? cnt : 64;
        u64 v = sbuf[wave][lane];
        u64 c = (lane < take) ? v : ~0ull;
        c = lane_sort64(c, lane);
        m = lane_merge64(m, c, lane);
        int rem = cnt - take;
        if (lane < rem) sbuf[wave][lane] = sbuf[wave][64 + lane];
        cnt = rem;
    }

    // lanes 0..31 hold the exact global top-32, ascending (== stable top_k)
    if (lane < KNN_K) {
        int n = (int)(u32)m;
        size_t o = (size_t)cid * (KNN_K * 3) + (size_t)lane * 3;
        out[o + 0] = __fsub_rn(xp[n], cx);
        out[o + 1] = __fsub_rn(yp[n], cy);
        out[o + 2] = __fsub_rn(zp[n], cz);
    }
}

extern "C" void kernel_launch(void* const* d_in, const int* in_sizes, int n_in,
                              void* d_out, int out_size, void* d_ws, size_t ws_size,
                              hipStream_t stream) {
    const float* in  = (const float*)d_in[0];
    float* out       = (float*)d_out;
    float* centers   = out + (size_t)BATCH * NGRP * KNN_K * 3;  // second output section

    fps_kernel<<<BATCH, FPS_T, 0, stream>>>(in, centers);
    knn_kernel<<<(BATCH * NGRP) / KNN_WPB, KNN_WPB * 64, 0, stream>>>(in, centers, out);
}